// Round 1
// 348.323 us; speedup vs baseline: 1.0632x; 1.0632x over previous
//
#include <hip/hip_runtime.h>
#include <cmath>

#define NLEVELS 16
#define HSIZE   (1 << 19)     // hashmap size, power of two
#define HMASK   (HSIZE - 1)

typedef float v2f __attribute__((ext_vector_type(2)));
typedef float v4f __attribute__((ext_vector_type(4)));

struct LevelParams {
    int res[NLEVELS];
    int r2mod[NLEVELS];       // (res*res) % HSIZE
};

__device__ __forceinline__ int hash_one(float x0, float x1, float x2, int res, int r2)
{
    const float fr = (float)res;
    int c0 = (int)floorf(x0 * fr); if (c0 >= res) c0 -= res;
    int c1 = (int)floorf(x1 * fr); if (c1 >= res) c1 -= res;
    int c2 = (int)floorf(x2 * fr); if (c2 >= res) c2 -= res;
    return (c0 + ((c1 * res) & HMASK) + ((c2 * r2) & HMASK)) & HMASK;
}

// ---------------- K1: two-phase heavy-level gather -----------------------
// Heavy levels (res>=80 touch ~the full 4 MB table) total ~46 MB of hot
// table data vs 33.5 MB aggregate L2 -> no single-pass partition fits.
// Time-partition instead:
//   phase A (blocks [0, blocksA)):  8 groups = levels 5..12, one 4 MB
//       table per XCD L2 (exact fit).
//   phase B (blocks [blocksA, ...)): levels 13/14/15 point-sharded
//       3/3/2-way -> still exactly one table per XCD, all XCDs busy.
// blocksA % 8 == 0 so blockIdx%8 -> XCD mapping holds across both phases.
// Light levels 0..4 (~2.5 MB combined) are handled in the finalize kernel.
__global__ __launch_bounds__(256)
void hashgrid_gather2(const float* __restrict__ x,
                      const float* __restrict__ emb,
                      v2f* __restrict__ ws,
                      LevelParams lp, int npts, int blocksA)
{
    __shared__ float sx[768];
    const int tid = threadIdx.x;

    int level, base, end;
    if ((int)blockIdx.x < blocksA) {
        const int g = blockIdx.x & 7;
        level = 5 + g;                        // levels 5..12
        base  = (int)(blockIdx.x >> 3) * 256;
        end   = npts;
    } else {
        const int idx = (int)blockIdx.x - blocksA;
        const int g   = idx & 7;              // == blockIdx.x % 8 since blocksA%8==0
        int shard, nsh;
        if (g < 3)      { level = 13; shard = g;     nsh = 3; }
        else if (g < 6) { level = 14; shard = g - 3; nsh = 3; }
        else            { level = 15; shard = g - 6; nsh = 2; }
        const int shardN = (npts + nsh - 1) / nsh;
        base = shard * shardN + (idx >> 3) * 256;
        end  = min(npts, (shard + 1) * shardN);
        if (base >= end) return;              // block-uniform: safe before barrier
    }

    const int nfl = npts * 3;
    const int b3  = base * 3;
    #pragma unroll
    for (int k = 0; k < 3; ++k) {
        const int idx = b3 + tid + k * 256;
        if (idx < nfl) sx[tid + k * 256] = __builtin_nontemporal_load(&x[idx]);
    }
    __syncthreads();

    const int p = base + tid;
    if (p >= end) return;

    const int h = hash_one(sx[tid * 3], sx[tid * 3 + 1], sx[tid * 3 + 2],
                           lp.res[level], lp.r2mod[level]);
    const v2f v = ((const v2f*)emb)[(size_t)level * HSIZE + h];
    __builtin_nontemporal_store(v, &ws[(size_t)level * npts + p]);
}

// ---------------- K2: LDS-tiled transpose + light-level gather -----------
// Per 256-point block: stage ws levels 5..15 with fully-contiguous
// 2 KB-per-level reads into LDS, then write out point-major (1 KB
// contiguous per wave). Lanes with j = tid&7 < 3 gather the cheap,
// L2-resident levels 0..4 inline (saves 5 levels of ws round-trip,
// 84 MB of HBM traffic).
__global__ __launch_bounds__(256)
void hashgrid_finalize(const float* __restrict__ x,
                       const float* __restrict__ emb,
                       const v2f* __restrict__ ws,
                       v4f* __restrict__ out4,
                       LevelParams lp, int npts)
{
    __shared__ float sx[768];
    __shared__ v2f   sl[11][257];   // +1 pad: phase-2 reads spread banks

    const int tid = threadIdx.x;
    const int p0  = (int)blockIdx.x * 256;

    const int nfl = npts * 3;
    const int b3  = p0 * 3;
    #pragma unroll
    for (int k = 0; k < 3; ++k) {
        const int idx = b3 + tid + k * 256;
        if (idx < nfl) sx[tid + k * 256] = __builtin_nontemporal_load(&x[idx]);
    }

    const int p = p0 + tid;
    v2f r[11];
    #pragma unroll
    for (int li = 0; li < 11; ++li) {
        r[li] = (p < npts)
              ? __builtin_nontemporal_load(&ws[(size_t)(5 + li) * npts + p])
              : (v2f)(0.0f);
    }
    #pragma unroll
    for (int li = 0; li < 11; ++li) sl[li][tid] = r[li];
    __syncthreads();

    const v2f* __restrict__ e2 = (const v2f*)emb;
    const int j  = tid & 7;     // static per thread: which float4 of the row
    const int tq = tid >> 3;

    #pragma unroll
    for (int k = 0; k < 8; ++k) {
        const int pp = k * 32 + tq;           // point within tile, 0..255
        const int pt = p0 + pp;
        if (pt < npts) {
            const float x0 = sx[pp * 3 + 0];
            const float x1 = sx[pp * 3 + 1];
            const float x2 = sx[pp * 3 + 2];
            v2f va, vb;
            if (j == 0) {
                va = e2[(size_t)0 * HSIZE + hash_one(x0, x1, x2, lp.res[0], lp.r2mod[0])];
                vb = e2[(size_t)1 * HSIZE + hash_one(x0, x1, x2, lp.res[1], lp.r2mod[1])];
            } else if (j == 1) {
                va = e2[(size_t)2 * HSIZE + hash_one(x0, x1, x2, lp.res[2], lp.r2mod[2])];
                vb = e2[(size_t)3 * HSIZE + hash_one(x0, x1, x2, lp.res[3], lp.r2mod[3])];
            } else if (j == 2) {
                va = e2[(size_t)4 * HSIZE + hash_one(x0, x1, x2, lp.res[4], lp.r2mod[4])];
                vb = sl[0][pp];               // level 5
            } else {
                va = sl[2 * j - 5][pp];       // levels 6,8,10,12,14
                vb = sl[2 * j - 4][pp];       // levels 7,9,11,13,15
            }
            v4f o; o.x = va.x; o.y = va.y; o.z = vb.x; o.w = vb.y;
            __builtin_nontemporal_store(o, &out4[(size_t)p0 * 8 + k * 256 + tid]);
        }
    }
}

// ---------------- fallback: proven round-1 single kernel -----------------
__global__ __launch_bounds__(256)
void hashgrid_fwd(const float* __restrict__ x,
                  const float* __restrict__ emb,
                  float* __restrict__ out,
                  LevelParams lp, int npts)
{
    __shared__ float sx[256 * 3];
    const int tid        = threadIdx.x;
    const int block_base = blockIdx.x * 256;
    const int nfl        = npts * 3;
    const int base3      = block_base * 3;
    #pragma unroll
    for (int k = 0; k < 3; ++k) {
        int idx = base3 + tid + k * 256;
        if (idx < nfl) sx[tid + k * 256] = x[idx];
    }
    __syncthreads();
    const int p = block_base + tid;
    if (p >= npts) return;
    const float x0 = sx[tid * 3 + 0], x1 = sx[tid * 3 + 1], x2 = sx[tid * 3 + 2];
    const float2* __restrict__ e2 = (const float2*)emb;
    float2 v[NLEVELS];
    #pragma unroll
    for (int l = 0; l < NLEVELS; ++l) {
        const int h = hash_one(x0, x1, x2, lp.res[l], lp.r2mod[l]);
        v[l] = e2[(size_t)l * HSIZE + h];
    }
    float4* __restrict__ o4 = (float4*)(out + (size_t)p * (NLEVELS * 2));
    #pragma unroll
    for (int i = 0; i < 8; ++i)
        o4[i] = make_float4(v[2 * i].x, v[2 * i].y, v[2 * i + 1].x, v[2 * i + 1].y);
}

extern "C" void kernel_launch(void* const* d_in, const int* in_sizes, int n_in,
                              void* d_out, int out_size, void* d_ws, size_t ws_size,
                              hipStream_t stream)
{
    const float* x   = (const float*)d_in[0];
    const float* emb = (const float*)d_in[1];
    float*       out = (float*)d_out;

    const int npts = in_sizes[0] / 3;

    // Host-double resolution computation, exact replica of the reference.
    LevelParams lp;
    const double s = std::exp((std::log(2048.0) - std::log(16.0)) / 15.0);
    for (int l = 0; l < NLEVELS; ++l) {
        const double r = 16.0 * std::pow(s, (double)l);
        const int res  = (int)r;
        lp.res[l]   = res;
        lp.r2mod[l] = (int)(((long long)res * res) % HSIZE);
    }

    const size_t ws_need = (size_t)NLEVELS * (size_t)npts * sizeof(v2f);
    if (ws_size >= ws_need) {
        const int cA      = (npts + 255) / 256;
        const int blocksA = cA * 8;               // levels 5..12, all points
        const int shardN2 = (npts + 1) / 2;       // largest phase-B shard (level 15 halves)
        const int cB      = (shardN2 + 255) / 256;
        const int grid1   = blocksA + cB * 8;
        hipLaunchKernelGGL(hashgrid_gather2, dim3(grid1), dim3(256), 0, stream,
                           x, emb, (v2f*)d_ws, lp, npts, blocksA);
        hipLaunchKernelGGL(hashgrid_finalize, dim3(cA), dim3(256), 0, stream,
                           x, emb, (const v2f*)d_ws, (v4f*)out, lp, npts);
    } else {
        const int blocks = (npts + 255) / 256;
        hipLaunchKernelGGL(hashgrid_fwd, dim3(blocks), dim3(256), 0, stream,
                           x, emb, out, lp, npts);
    }
}

// Round 2
// 337.870 us; speedup vs baseline: 1.0961x; 1.0309x over previous
//
#include <hip/hip_runtime.h>
#include <cmath>

#define NLEVELS 16
#define HSIZE   (1 << 19)     // hashmap size, power of two
#define HMASK   (HSIZE - 1)

typedef float v2f __attribute__((ext_vector_type(2)));
typedef float v4f __attribute__((ext_vector_type(4)));

struct LevelParams {
    int res[NLEVELS];
    int r2mod[NLEVELS];       // (res*res) % HSIZE
};

__device__ __forceinline__ int hash_one(float x0, float x1, float x2, int res, int r2)
{
    const float fr = (float)res;
    int c0 = (int)floorf(x0 * fr); if (c0 >= res) c0 -= res;
    int c1 = (int)floorf(x1 * fr); if (c1 >= res) c1 -= res;
    int c2 = (int)floorf(x2 * fr); if (c2 >= res) c2 -= res;
    return (c0 + ((c1 * res) & HMASK) + ((c2 * r2) & HMASK)) & HMASK;
}

// ---------------- K1: two-phase heavy-level gather, MLP=4 ----------------
// Heavy levels 5..15 time-partitioned so each XCD's L2 holds exactly ONE
// <=4 MB table at a time:
//   phase A (blocks [0, blocksA)):  8 groups = levels 5..12.
//   phase B: levels 13/14/15 point-sharded 3/3/2-way across the 8 groups.
// blocksA % 8 == 0 so blockIdx%8 -> XCD mapping holds across both phases.
// Each thread now handles 4 points (4 independent L2 gathers in flight) —
// round-2 counters showed MLP=1 left the kernel latency-bound at 21% HBM.
#define K1_PPT   4
#define K1_CHUNK (256 * K1_PPT)   // 1024 points per block

__global__ __launch_bounds__(256)
void hashgrid_gather2(const float* __restrict__ x,
                      const float* __restrict__ emb,
                      v2f* __restrict__ ws,
                      LevelParams lp, int npts, int blocksA)
{
    __shared__ float sx[K1_CHUNK * 3];   // 12 KB
    const int tid = threadIdx.x;

    int level, base, end;
    if ((int)blockIdx.x < blocksA) {
        const int g = blockIdx.x & 7;
        level = 5 + g;                        // levels 5..12
        base  = (int)(blockIdx.x >> 3) * K1_CHUNK;
        end   = npts;
        if (base >= npts) return;
    } else {
        const int idx = (int)blockIdx.x - blocksA;
        const int g   = idx & 7;              // == blockIdx.x % 8 since blocksA%8==0
        int shard, nsh;
        if (g < 3)      { level = 13; shard = g;     nsh = 3; }
        else if (g < 6) { level = 14; shard = g - 3; nsh = 3; }
        else            { level = 15; shard = g - 6; nsh = 2; }
        const int shardN = (npts + nsh - 1) / nsh;
        base = shard * shardN + (idx >> 3) * K1_CHUNK;
        end  = min(npts, (shard + 1) * shardN);
        if (base >= end) return;              // block-uniform: safe before barrier
    }

    const int nfl = npts * 3;
    const int b3  = base * 3;
    #pragma unroll
    for (int k = 0; k < 3 * K1_PPT; ++k) {
        const int idx = b3 + tid + k * 256;
        if (idx < nfl) sx[tid + k * 256] = __builtin_nontemporal_load(&x[idx]);
    }
    __syncthreads();

    const int res = lp.res[level];
    const int r2  = lp.r2mod[level];
    const v2f* __restrict__ e2 = (const v2f*)emb + (size_t)level * HSIZE;
    v2f* __restrict__ wl = ws + (size_t)level * npts;

    v2f v[K1_PPT];
    int pg[K1_PPT];
    #pragma unroll
    for (int k = 0; k < K1_PPT; ++k) {
        const int pl = tid + k * 256;         // local point 0..1023
        const int p  = base + pl;
        pg[k] = p;
        if (p < end) {
            const int h = hash_one(sx[pl * 3], sx[pl * 3 + 1], sx[pl * 3 + 2], res, r2);
            v[k] = e2[h];
        }
    }
    #pragma unroll
    for (int k = 0; k < K1_PPT; ++k)
        if (pg[k] < end)
            __builtin_nontemporal_store(v[k], &wl[pg[k]]);
}

// ---------------- K2: full-lane light gather + LDS transpose -------------
// Round-2 version gathered levels 0..4 inside diverged j==0/1/2 branches
// (8/64 active lanes per gather instruction) — it cost ~208 us. Now every
// thread gathers levels 0..4 for ITS OWN point (full 64-lane instructions,
// 5 independent gathers in flight), all 16 levels land in LDS, then the
// wave writes point-major 1 KB-contiguous float4 lines.
__global__ __launch_bounds__(256)
void hashgrid_finalize(const float* __restrict__ x,
                       const float* __restrict__ emb,
                       const v2f* __restrict__ ws,
                       v4f* __restrict__ out4,
                       LevelParams lp, int npts)
{
    __shared__ float sx[768];
    __shared__ v2f   sl[16][257];   // 32.9 KB; +1 pad spreads transpose banks

    const int tid = threadIdx.x;
    const int p0  = (int)blockIdx.x * 256;

    const int nfl = npts * 3;
    const int b3  = p0 * 3;
    #pragma unroll
    for (int k = 0; k < 3; ++k) {
        const int idx = b3 + tid + k * 256;
        if (idx < nfl) sx[tid + k * 256] = __builtin_nontemporal_load(&x[idx]);
    }
    __syncthreads();

    const int  p     = p0 + tid;
    const bool valid = (p < npts);
    const v2f* __restrict__ e2 = (const v2f*)emb;

    const float x0 = sx[tid * 3 + 0];
    const float x1 = sx[tid * 3 + 1];
    const float x2 = sx[tid * 3 + 2];

    // light levels 0..4: own-point gathers, tables ~2.5 MB total (L2-hot)
    v2f g[5];
    #pragma unroll
    for (int l = 0; l < 5; ++l) {
        g[l] = valid
             ? e2[(size_t)l * HSIZE + hash_one(x0, x1, x2, lp.res[l], lp.r2mod[l])]
             : (v2f)(0.0f);
    }
    // heavy levels 5..15 from workspace: fully contiguous 2 KB per level
    v2f r[11];
    #pragma unroll
    for (int li = 0; li < 11; ++li) {
        r[li] = valid
              ? __builtin_nontemporal_load(&ws[(size_t)(5 + li) * npts + p])
              : (v2f)(0.0f);
    }

    #pragma unroll
    for (int l = 0; l < 5; ++l)  sl[l][tid]      = g[l];
    #pragma unroll
    for (int li = 0; li < 11; ++li) sl[5 + li][tid] = r[li];
    __syncthreads();

    const int j  = tid & 7;     // which float4 of the 32-float output row
    const int tq = tid >> 3;

    #pragma unroll
    for (int k = 0; k < 8; ++k) {
        const int pp = k * 32 + tq;           // point within tile, 0..255
        if (p0 + pp < npts) {
            const v2f va = sl[2 * j][pp];
            const v2f vb = sl[2 * j + 1][pp];
            v4f o; o.x = va.x; o.y = va.y; o.z = vb.x; o.w = vb.y;
            __builtin_nontemporal_store(o, &out4[(size_t)p0 * 8 + k * 256 + tid]);
        }
    }
}

// ---------------- fallback: proven round-1 single kernel -----------------
__global__ __launch_bounds__(256)
void hashgrid_fwd(const float* __restrict__ x,
                  const float* __restrict__ emb,
                  float* __restrict__ out,
                  LevelParams lp, int npts)
{
    __shared__ float sx[256 * 3];
    const int tid        = threadIdx.x;
    const int block_base = blockIdx.x * 256;
    const int nfl        = npts * 3;
    const int base3      = block_base * 3;
    #pragma unroll
    for (int k = 0; k < 3; ++k) {
        int idx = base3 + tid + k * 256;
        if (idx < nfl) sx[tid + k * 256] = x[idx];
    }
    __syncthreads();
    const int p = block_base + tid;
    if (p >= npts) return;
    const float x0 = sx[tid * 3 + 0], x1 = sx[tid * 3 + 1], x2 = sx[tid * 3 + 2];
    const float2* __restrict__ e2 = (const float2*)emb;
    float2 v[NLEVELS];
    #pragma unroll
    for (int l = 0; l < NLEVELS; ++l) {
        const int h = hash_one(x0, x1, x2, lp.res[l], lp.r2mod[l]);
        v[l] = e2[(size_t)l * HSIZE + h];
    }
    float4* __restrict__ o4 = (float4*)(out + (size_t)p * (NLEVELS * 2));
    #pragma unroll
    for (int i = 0; i < 8; ++i)
        o4[i] = make_float4(v[2 * i].x, v[2 * i].y, v[2 * i + 1].x, v[2 * i + 1].y);
}

extern "C" void kernel_launch(void* const* d_in, const int* in_sizes, int n_in,
                              void* d_out, int out_size, void* d_ws, size_t ws_size,
                              hipStream_t stream)
{
    const float* x   = (const float*)d_in[0];
    const float* emb = (const float*)d_in[1];
    float*       out = (float*)d_out;

    const int npts = in_sizes[0] / 3;

    // Host-double resolution computation, exact replica of the reference.
    LevelParams lp;
    const double s = std::exp((std::log(2048.0) - std::log(16.0)) / 15.0);
    for (int l = 0; l < NLEVELS; ++l) {
        const double r = 16.0 * std::pow(s, (double)l);
        const int res  = (int)r;
        lp.res[l]   = res;
        lp.r2mod[l] = (int)(((long long)res * res) % HSIZE);
    }

    const size_t ws_need = (size_t)NLEVELS * (size_t)npts * sizeof(v2f);
    if (ws_size >= ws_need) {
        const int cA      = (npts + K1_CHUNK - 1) / K1_CHUNK;
        const int blocksA = cA * 8;               // levels 5..12, all points
        const int shardN2 = (npts + 1) / 2;       // largest phase-B shard (level 15 halves)
        const int cB      = (shardN2 + K1_CHUNK - 1) / K1_CHUNK;
        const int grid1   = blocksA + cB * 8;
        hipLaunchKernelGGL(hashgrid_gather2, dim3(grid1), dim3(256), 0, stream,
                           x, emb, (v2f*)d_ws, lp, npts, blocksA);
        const int grid2 = (npts + 255) / 256;
        hipLaunchKernelGGL(hashgrid_finalize, dim3(grid2), dim3(256), 0, stream,
                           x, emb, (const v2f*)d_ws, (v4f*)out, lp, npts);
    } else {
        const int blocks = (npts + 255) / 256;
        hipLaunchKernelGGL(hashgrid_fwd, dim3(blocks), dim3(256), 0, stream,
                           x, emb, out, lp, npts);
    }
}

// Round 3
// 332.131 us; speedup vs baseline: 1.1150x; 1.0173x over previous
//
#include <hip/hip_runtime.h>
#include <cmath>

#define NLEVELS 16
#define HSIZE   (1 << 19)     // hashmap size, power of two
#define HMASK   (HSIZE - 1)

typedef float v2f __attribute__((ext_vector_type(2)));
typedef float v4f __attribute__((ext_vector_type(4)));

struct LevelParams {
    int res[NLEVELS];
    int r2mod[NLEVELS];       // (res*res) % HSIZE
};

__device__ __forceinline__ int hash_one(float x0, float x1, float x2, int res, int r2)
{
    const float fr = (float)res;
    int c0 = (int)floorf(x0 * fr); if (c0 >= res) c0 -= res;
    int c1 = (int)floorf(x1 * fr); if (c1 >= res) c1 -= res;
    int c2 = (int)floorf(x2 * fr); if (c2 >= res) c2 -= res;
    return (c0 + ((c1 * res) & HMASK) + ((c2 * r2) & HMASK)) & HMASK;
}

// ---------------- K1: two-phase heavy-level gather, MLP=4 ----------------
// Heavy levels 5..15 time-partitioned so each XCD's L2 holds exactly ONE
// <=4 MB table at a time (FETCH counters confirm tables cold-miss once):
//   phase A (blocks [0, blocksA)):  8 groups = levels 5..12.
//   phase B: levels 13/14/15 point-sharded 3/3/2-way across the 8 groups.
// blocksA % 8 == 0 so blockIdx%8 -> XCD mapping holds across both phases.
//
// Round-3 change: x loads are CACHED (were nontemporal). x is 12.6 MB and
// re-read 9x -> the 256 MB L3 serves the repeats. nt stays ONLY on the ws
// stores, which must not thrash the per-XCD L2 table residency.
#define K1_PPT   4
#define K1_CHUNK (256 * K1_PPT)   // 1024 points per block

__global__ __launch_bounds__(256)
void hashgrid_gather2(const float* __restrict__ x,
                      const float* __restrict__ emb,
                      v2f* __restrict__ ws,
                      LevelParams lp, int npts, int blocksA)
{
    __shared__ float sx[K1_CHUNK * 3];   // 12 KB
    const int tid = threadIdx.x;

    int level, base, end;
    if ((int)blockIdx.x < blocksA) {
        const int g = blockIdx.x & 7;
        level = 5 + g;                        // levels 5..12
        base  = (int)(blockIdx.x >> 3) * K1_CHUNK;
        end   = npts;
        if (base >= npts) return;
    } else {
        const int idx = (int)blockIdx.x - blocksA;
        const int g   = idx & 7;              // == blockIdx.x % 8 since blocksA%8==0
        int shard, nsh;
        if (g < 3)      { level = 13; shard = g;     nsh = 3; }
        else if (g < 6) { level = 14; shard = g - 3; nsh = 3; }
        else            { level = 15; shard = g - 6; nsh = 2; }
        const int shardN = (npts + nsh - 1) / nsh;
        base = shard * shardN + (idx >> 3) * K1_CHUNK;
        end  = min(npts, (shard + 1) * shardN);
        if (base >= end) return;              // block-uniform: safe before barrier
    }

    const int nfl = npts * 3;
    const int b3  = base * 3;
    #pragma unroll
    for (int k = 0; k < 3 * K1_PPT; ++k) {
        const int idx = b3 + tid + k * 256;
        if (idx < nfl) sx[tid + k * 256] = x[idx];     // cached: L3 serves re-reads
    }
    __syncthreads();

    const int res = lp.res[level];
    const int r2  = lp.r2mod[level];
    const v2f* __restrict__ e2 = (const v2f*)emb + (size_t)level * HSIZE;
    v2f* __restrict__ wl = ws + (size_t)level * npts;

    v2f v[K1_PPT];
    int pg[K1_PPT];
    #pragma unroll
    for (int k = 0; k < K1_PPT; ++k) {
        const int pl = tid + k * 256;         // local point 0..1023
        const int p  = base + pl;
        pg[k] = p;
        if (p < end) {
            const int h = hash_one(sx[pl * 3], sx[pl * 3 + 1], sx[pl * 3 + 2], res, r2);
            v[k] = e2[h];
        }
    }
    #pragma unroll
    for (int k = 0; k < K1_PPT; ++k)
        if (pg[k] < end)
            __builtin_nontemporal_store(v[k], &wl[pg[k]]);   // nt: protect L2 tables
}

// ---------------- K2: full-lane light gather + LDS transpose -------------
// Every thread gathers levels 0..4 for its own point (full 64-lane
// instructions, tables ~2.4 MB total -> L2-resident everywhere), reads the
// heavy levels from ws (CACHED now: 92 MB fits L3, K1's stores may still
// be on-die), stages all 16 levels in LDS, then each wave writes
// point-major 1 KB-contiguous float4 lines. nt only on the final stores.
__global__ __launch_bounds__(256)
void hashgrid_finalize(const float* __restrict__ x,
                       const float* __restrict__ emb,
                       const v2f* __restrict__ ws,
                       v4f* __restrict__ out4,
                       LevelParams lp, int npts)
{
    __shared__ float sx[768];
    __shared__ v2f   sl[16][257];   // 32.9 KB; +1 pad spreads transpose banks

    const int tid = threadIdx.x;
    const int p0  = (int)blockIdx.x * 256;

    const int nfl = npts * 3;
    const int b3  = p0 * 3;
    #pragma unroll
    for (int k = 0; k < 3; ++k) {
        const int idx = b3 + tid + k * 256;
        if (idx < nfl) sx[tid + k * 256] = x[idx];
    }
    __syncthreads();

    const int  p     = p0 + tid;
    const bool valid = (p < npts);
    const v2f* __restrict__ e2 = (const v2f*)emb;

    const float x0 = sx[tid * 3 + 0];
    const float x1 = sx[tid * 3 + 1];
    const float x2 = sx[tid * 3 + 2];

    // heavy levels 5..15 from workspace: fully contiguous 2 KB per level,
    // issued first so they're in flight under the hash math
    v2f r[11];
    #pragma unroll
    for (int li = 0; li < 11; ++li) {
        r[li] = valid ? ws[(size_t)(5 + li) * npts + p] : (v2f)(0.0f);
    }
    // light levels 0..4: own-point gathers, L2-hot tables
    v2f g[5];
    #pragma unroll
    for (int l = 0; l < 5; ++l) {
        g[l] = valid
             ? e2[(size_t)l * HSIZE + hash_one(x0, x1, x2, lp.res[l], lp.r2mod[l])]
             : (v2f)(0.0f);
    }

    #pragma unroll
    for (int l = 0; l < 5; ++l)     sl[l][tid]      = g[l];
    #pragma unroll
    for (int li = 0; li < 11; ++li) sl[5 + li][tid] = r[li];
    __syncthreads();

    const int j  = tid & 7;     // which float4 of the 32-float output row
    const int tq = tid >> 3;

    #pragma unroll
    for (int k = 0; k < 8; ++k) {
        const int pp = k * 32 + tq;           // point within tile, 0..255
        if (p0 + pp < npts) {
            const v2f va = sl[2 * j][pp];
            const v2f vb = sl[2 * j + 1][pp];
            v4f o; o.x = va.x; o.y = va.y; o.z = vb.x; o.w = vb.y;
            __builtin_nontemporal_store(o, &out4[(size_t)p0 * 8 + k * 256 + tid]);
        }
    }
}

// ---------------- fallback: proven round-1 single kernel -----------------
__global__ __launch_bounds__(256)
void hashgrid_fwd(const float* __restrict__ x,
                  const float* __restrict__ emb,
                  float* __restrict__ out,
                  LevelParams lp, int npts)
{
    __shared__ float sx[256 * 3];
    const int tid        = threadIdx.x;
    const int block_base = blockIdx.x * 256;
    const int nfl        = npts * 3;
    const int base3      = block_base * 3;
    #pragma unroll
    for (int k = 0; k < 3; ++k) {
        int idx = base3 + tid + k * 256;
        if (idx < nfl) sx[tid + k * 256] = x[idx];
    }
    __syncthreads();
    const int p = block_base + tid;
    if (p >= npts) return;
    const float x0 = sx[tid * 3 + 0], x1 = sx[tid * 3 + 1], x2 = sx[tid * 3 + 2];
    const float2* __restrict__ e2 = (const float2*)emb;
    float2 v[NLEVELS];
    #pragma unroll
    for (int l = 0; l < NLEVELS; ++l) {
        const int h = hash_one(x0, x1, x2, lp.res[l], lp.r2mod[l]);
        v[l] = e2[(size_t)l * HSIZE + h];
    }
    float4* __restrict__ o4 = (float4*)(out + (size_t)p * (NLEVELS * 2));
    #pragma unroll
    for (int i = 0; i < 8; ++i)
        o4[i] = make_float4(v[2 * i].x, v[2 * i].y, v[2 * i + 1].x, v[2 * i + 1].y);
}

extern "C" void kernel_launch(void* const* d_in, const int* in_sizes, int n_in,
                              void* d_out, int out_size, void* d_ws, size_t ws_size,
                              hipStream_t stream)
{
    const float* x   = (const float*)d_in[0];
    const float* emb = (const float*)d_in[1];
    float*       out = (float*)d_out;

    const int npts = in_sizes[0] / 3;

    // Host-double resolution computation, exact replica of the reference.
    LevelParams lp;
    const double s = std::exp((std::log(2048.0) - std::log(16.0)) / 15.0);
    for (int l = 0; l < NLEVELS; ++l) {
        const double r = 16.0 * std::pow(s, (double)l);
        const int res  = (int)r;
        lp.res[l]   = res;
        lp.r2mod[l] = (int)(((long long)res * res) % HSIZE);
    }

    const size_t ws_need = (size_t)NLEVELS * (size_t)npts * sizeof(v2f);
    if (ws_size >= ws_need) {
        const int cA      = (npts + K1_CHUNK - 1) / K1_CHUNK;
        const int blocksA = cA * 8;               // levels 5..12, all points
        const int shardN2 = (npts + 1) / 2;       // largest phase-B shard (level 15 halves)
        const int cB      = (shardN2 + K1_CHUNK - 1) / K1_CHUNK;
        const int grid1   = blocksA + cB * 8;
        hipLaunchKernelGGL(hashgrid_gather2, dim3(grid1), dim3(256), 0, stream,
                           x, emb, (v2f*)d_ws, lp, npts, blocksA);
        const int grid2 = (npts + 255) / 256;
        hipLaunchKernelGGL(hashgrid_finalize, dim3(grid2), dim3(256), 0, stream,
                           x, emb, (const v2f*)d_ws, (v4f*)out, lp, npts);
    } else {
        const int blocks = (npts + 255) / 256;
        hipLaunchKernelGGL(hashgrid_fwd, dim3(blocks), dim3(256), 0, stream,
                           x, emb, out, lp, npts);
    }
}

// Round 4
// 315.647 us; speedup vs baseline: 1.1733x; 1.0522x over previous
//
#include <hip/hip_runtime.h>
#include <cmath>

#define NLEVELS 16
#define HSIZE   (1 << 19)     // hashmap size, power of two
#define HMASK   (HSIZE - 1)

typedef float v2f __attribute__((ext_vector_type(2)));
typedef float v4f __attribute__((ext_vector_type(4)));

struct LevelParams {
    int res[NLEVELS];
    int r2mod[NLEVELS];       // (res*res) % HSIZE
};

__device__ __forceinline__ int hash_one(float x0, float x1, float x2, int res, int r2)
{
    const float fr = (float)res;
    int c0 = (int)floorf(x0 * fr); if (c0 >= res) c0 -= res;
    int c1 = (int)floorf(x1 * fr); if (c1 >= res) c1 -= res;
    int c2 = (int)floorf(x2 * fr); if (c2 >= res) c2 -= res;
    return (c0 + ((c1 * res) & HMASK) + ((c2 * r2) & HMASK)) & HMASK;
}

// ---------------- K1: two-phase heavy-level gather, MLP=8 ----------------
// Heavy levels 5..15 time-partitioned so each XCD's L2 holds exactly ONE
// <=4 MB table at a time:
//   phase A (blocks [0, blocksA)):  8 groups = levels 5..12.
//   phase B: levels 13/14/15 point-sharded 3/3/2-way across the 8 groups
//            (shard bases rounded to K1_CHUNK so float4 staging stays aligned).
// blocksA % 8 == 0 so blockIdx%8 -> XCD mapping holds across both phases.
//
// Round 0-3 counters: lane-gather rate pinned at 82-100 G/s chip for any
// structure -> per-CU miss-concurrency wall (~49 outstanding, Little's law).
// Round 4: PPT 4->8 (2x in-flight gathers/wave; 24 KB LDS still gives
// ~6 blocks/CU = same occupancy), float4 x staging (6 loads vs 24).
#define K1_PPT   8
#define K1_CHUNK (256 * K1_PPT)   // 2048 points per block

__global__ __launch_bounds__(256)
void hashgrid_gather2(const float* __restrict__ x,
                      const float* __restrict__ emb,
                      v2f* __restrict__ ws,
                      LevelParams lp, int npts, int blocksA)
{
    __shared__ float sx[K1_CHUNK * 3];   // 24 KB
    const int tid = threadIdx.x;

    int level, base, end;
    if ((int)blockIdx.x < blocksA) {
        const int g = blockIdx.x & 7;
        level = 5 + g;                        // levels 5..12
        base  = (int)(blockIdx.x >> 3) * K1_CHUNK;
        end   = npts;
        if (base >= npts) return;
    } else {
        const int idx = (int)blockIdx.x - blocksA;
        const int g   = idx & 7;              // == blockIdx.x % 8 since blocksA%8==0
        int shard, nsh;
        if (g < 3)      { level = 13; shard = g;     nsh = 3; }
        else if (g < 6) { level = 14; shard = g - 3; nsh = 3; }
        else            { level = 15; shard = g - 6; nsh = 2; }
        // shard size rounded up to a whole chunk: keeps base K1_CHUNK-aligned
        const int shardN = (((npts + nsh - 1) / nsh + K1_CHUNK - 1) / K1_CHUNK) * K1_CHUNK;
        base = shard * shardN + (idx >> 3) * K1_CHUNK;
        end  = min(npts, (shard + 1) * shardN);
        if (base >= end) return;              // block-uniform: safe before barrier
    }

    const int nfl = npts * 3;
    const int b3  = base * 3;                 // base%2048==0 -> b3*4 is 16B-aligned
    {
        const float4* __restrict__ x4 = (const float4*)(x + b3);
        float4* __restrict__ sx4 = (float4*)sx;
        #pragma unroll
        for (int k = 0; k < (3 * K1_PPT) / 4; ++k) {
            const int e  = tid + k * 256;     // float4 index within chunk
            const int f0 = b3 + e * 4;        // first float index
            if (f0 + 3 < nfl) {
                sx4[e] = x4[e];               // cached: L3 serves cross-XCD re-reads
            } else {
                #pragma unroll
                for (int j = 0; j < 4; ++j)
                    if (f0 + j < nfl) sx[e * 4 + j] = x[f0 + j];
            }
        }
    }
    __syncthreads();

    const int res = lp.res[level];
    const int r2  = lp.r2mod[level];
    const v2f* __restrict__ e2 = (const v2f*)emb + (size_t)level * HSIZE;
    v2f* __restrict__ wl = ws + (size_t)level * npts;

    v2f v[K1_PPT];
    #pragma unroll
    for (int k = 0; k < K1_PPT; ++k) {
        const int pl = tid + k * 256;         // local point 0..K1_CHUNK-1
        if (base + pl < end) {
            const int h = hash_one(sx[pl * 3], sx[pl * 3 + 1], sx[pl * 3 + 2], res, r2);
            v[k] = e2[h];
        }
    }
    #pragma unroll
    for (int k = 0; k < K1_PPT; ++k) {
        const int p = base + tid + k * 256;
        if (p < end)
            __builtin_nontemporal_store(v[k], &wl[p]);   // nt: protect L2 tables
    }
}

// ---------------- K2: full-lane light gather + LDS transpose -------------
// Reads heavy levels 5..15 from ws with NT streams (round-3 cached them:
// 92 MB of streaming evicted the 2.1 MB light tables from L2, putting the
// 5 light gathers at L3 latency inside the same miss-concurrency pool).
// ws streams are issued FIRST so they fly under the hash math + gathers.
// x is read directly (no LDS stage / no first barrier). All 16 levels land
// in LDS, then each wave writes point-major 1 KB-contiguous float4 lines.
__global__ __launch_bounds__(256)
void hashgrid_finalize(const float* __restrict__ x,
                       const float* __restrict__ emb,
                       const v2f* __restrict__ ws,
                       v4f* __restrict__ out4,
                       LevelParams lp, int npts)
{
    __shared__ v2f sl[16][257];   // 32.9 KB; +1 pad spreads transpose banks

    const int tid = threadIdx.x;
    const int p0  = (int)blockIdx.x * 256;
    const int  p     = p0 + tid;
    const bool valid = (p < npts);

    // heavy levels 5..15 from workspace: fully contiguous 512 B per wave,
    // nt (stream-once: don't evict light tables from L2)
    v2f r[11];
    #pragma unroll
    for (int li = 0; li < 11; ++li) {
        r[li] = valid
              ? __builtin_nontemporal_load(&ws[(size_t)(5 + li) * npts + p])
              : (v2f)(0.0f);
    }

    const float x0 = valid ? x[p * 3 + 0] : 0.0f;
    const float x1 = valid ? x[p * 3 + 1] : 0.0f;
    const float x2 = valid ? x[p * 3 + 2] : 0.0f;

    // light levels 0..4: own-point gathers, ~2.1 MB hot set (L2-resident)
    v2f g[5];
    #pragma unroll
    for (int l = 0; l < 5; ++l) {
        g[l] = valid
             ? ((const v2f*)emb)[(size_t)l * HSIZE + hash_one(x0, x1, x2, lp.res[l], lp.r2mod[l])]
             : (v2f)(0.0f);
    }

    #pragma unroll
    for (int l = 0; l < 5; ++l)     sl[l][tid]      = g[l];
    #pragma unroll
    for (int li = 0; li < 11; ++li) sl[5 + li][tid] = r[li];
    __syncthreads();

    const int j  = tid & 7;     // which float4 of the 32-float output row
    const int tq = tid >> 3;

    #pragma unroll
    for (int k = 0; k < 8; ++k) {
        const int pp = k * 32 + tq;           // point within tile, 0..255
        if (p0 + pp < npts) {
            const v2f va = sl[2 * j][pp];
            const v2f vb = sl[2 * j + 1][pp];
            v4f o; o.x = va.x; o.y = va.y; o.z = vb.x; o.w = vb.y;
            __builtin_nontemporal_store(o, &out4[(size_t)p0 * 8 + k * 256 + tid]);
        }
    }
}

// ---------------- fallback: proven round-1 single kernel -----------------
__global__ __launch_bounds__(256)
void hashgrid_fwd(const float* __restrict__ x,
                  const float* __restrict__ emb,
                  float* __restrict__ out,
                  LevelParams lp, int npts)
{
    __shared__ float sx[256 * 3];
    const int tid        = threadIdx.x;
    const int block_base = blockIdx.x * 256;
    const int nfl        = npts * 3;
    const int base3      = block_base * 3;
    #pragma unroll
    for (int k = 0; k < 3; ++k) {
        int idx = base3 + tid + k * 256;
        if (idx < nfl) sx[tid + k * 256] = x[idx];
    }
    __syncthreads();
    const int p = block_base + tid;
    if (p >= npts) return;
    const float x0 = sx[tid * 3 + 0], x1 = sx[tid * 3 + 1], x2 = sx[tid * 3 + 2];
    const float2* __restrict__ e2 = (const float2*)emb;
    float2 v[NLEVELS];
    #pragma unroll
    for (int l = 0; l < NLEVELS; ++l) {
        const int h = hash_one(x0, x1, x2, lp.res[l], lp.r2mod[l]);
        v[l] = e2[(size_t)l * HSIZE + h];
    }
    float4* __restrict__ o4 = (float4*)(out + (size_t)p * (NLEVELS * 2));
    #pragma unroll
    for (int i = 0; i < 8; ++i)
        o4[i] = make_float4(v[2 * i].x, v[2 * i].y, v[2 * i + 1].x, v[2 * i + 1].y);
}

extern "C" void kernel_launch(void* const* d_in, const int* in_sizes, int n_in,
                              void* d_out, int out_size, void* d_ws, size_t ws_size,
                              hipStream_t stream)
{
    const float* x   = (const float*)d_in[0];
    const float* emb = (const float*)d_in[1];
    float*       out = (float*)d_out;

    const int npts = in_sizes[0] / 3;

    // Host-double resolution computation, exact replica of the reference.
    LevelParams lp;
    const double s = std::exp((std::log(2048.0) - std::log(16.0)) / 15.0);
    for (int l = 0; l < NLEVELS; ++l) {
        const double r = 16.0 * std::pow(s, (double)l);
        const int res  = (int)r;
        lp.res[l]   = res;
        lp.r2mod[l] = (int)(((long long)res * res) % HSIZE);
    }

    const size_t ws_need = (size_t)NLEVELS * (size_t)npts * sizeof(v2f);
    if (ws_size >= ws_need) {
        const int cA      = (npts + K1_CHUNK - 1) / K1_CHUNK;
        const int blocksA = cA * 8;               // levels 5..12, all points
        // phase-B grid: sized by the largest shard (level 15, nsh=2)
        const int shardN2 = (((npts + 1) / 2 + K1_CHUNK - 1) / K1_CHUNK) * K1_CHUNK;
        const int cB      = (shardN2 + K1_CHUNK - 1) / K1_CHUNK;
        const int grid1   = blocksA + cB * 8;
        hipLaunchKernelGGL(hashgrid_gather2, dim3(grid1), dim3(256), 0, stream,
                           x, emb, (v2f*)d_ws, lp, npts, blocksA);
        const int grid2 = (npts + 255) / 256;
        hipLaunchKernelGGL(hashgrid_finalize, dim3(grid2), dim3(256), 0, stream,
                           x, emb, (const v2f*)d_ws, (v4f*)out, lp, npts);
    } else {
        const int blocks = (npts + 255) / 256;
        hipLaunchKernelGGL(hashgrid_fwd, dim3(blocks), dim3(256), 0, stream,
                           x, emb, out, lp, npts);
    }
}

// Round 5
// 313.470 us; speedup vs baseline: 1.1814x; 1.0069x over previous
//
#include <hip/hip_runtime.h>
#include <cmath>

#define NLEVELS 16
#define HSIZE   (1 << 19)     // hashmap size, power of two
#define HMASK   (HSIZE - 1)

typedef float v2f __attribute__((ext_vector_type(2)));
typedef float v4f __attribute__((ext_vector_type(4)));

struct LevelParams {
    int res[NLEVELS];
    int r2mod[NLEVELS];       // (res*res) % HSIZE
};

__device__ __forceinline__ int hash_one(float x0, float x1, float x2, int res, int r2)
{
    const float fr = (float)res;
    int c0 = (int)floorf(x0 * fr); if (c0 >= res) c0 -= res;
    int c1 = (int)floorf(x1 * fr); if (c1 >= res) c1 -= res;
    int c2 = (int)floorf(x2 * fr); if (c2 >= res) c2 -= res;
    return (c0 + ((c1 * res) & HMASK) + ((c2 * r2) & HMASK)) & HMASK;
}

// ---------------- K1: 9-level gather (levels 7..15) ----------------------
// Rounds 0-4 established: lane-gather rate is pinned at ~100 G/s chip-wide
// (per-CU MSHR x latency wall) regardless of occupancy/MLP/partition, and
// total-minus-K1 is ~205 us FIXED overhead. So K1 time ~ gather count.
// Round 5: shrink K1 from 11 to 9 levels (5,6 move to K2, which has slack).
//   phase A (blocks [0, blocksA)): levels 7..14, one 4 MB table per XCD L2.
//   phase B: level 15 point-sharded 8-way (table L2-resident in all XCDs).
// blocksA % 8 == 0 so blockIdx%8 -> XCD mapping holds across both phases.
#define K1_PPT   8
#define K1_CHUNK (256 * K1_PPT)   // 2048 points per block

__global__ __launch_bounds__(256)
void hashgrid_gather2(const float* __restrict__ x,
                      const float* __restrict__ emb,
                      v2f* __restrict__ ws,
                      LevelParams lp, int npts, int blocksA)
{
    __shared__ float sx[K1_CHUNK * 3];   // 24 KB
    const int tid = threadIdx.x;

    int level, base, end;
    if ((int)blockIdx.x < blocksA) {
        const int g = blockIdx.x & 7;
        level = 7 + g;                        // levels 7..14
        base  = (int)(blockIdx.x >> 3) * K1_CHUNK;
        end   = npts;
        if (base >= npts) return;
    } else {
        const int idx = (int)blockIdx.x - blocksA;
        const int g   = idx & 7;              // XCD id; also the point shard
        level = 15;
        // shard size rounded up to a whole chunk: keeps base K1_CHUNK-aligned
        const int shardN = (((npts + 7) / 8 + K1_CHUNK - 1) / K1_CHUNK) * K1_CHUNK;
        base = g * shardN + (idx >> 3) * K1_CHUNK;
        end  = min(npts, (g + 1) * shardN);
        if (base >= end) return;              // block-uniform: safe before barrier
    }

    const int nfl = npts * 3;
    const int b3  = base * 3;                 // base%2048==0 -> 16B-aligned
    {
        const float4* __restrict__ x4 = (const float4*)(x + b3);
        float4* __restrict__ sx4 = (float4*)sx;
        #pragma unroll
        for (int k = 0; k < (3 * K1_PPT) / 4; ++k) {
            const int e  = tid + k * 256;     // float4 index within chunk
            const int f0 = b3 + e * 4;        // first float index
            if (f0 + 3 < nfl) {
                sx4[e] = x4[e];               // cached: L3 serves cross-XCD re-reads
            } else {
                #pragma unroll
                for (int j = 0; j < 4; ++j)
                    if (f0 + j < nfl) sx[e * 4 + j] = x[f0 + j];
            }
        }
    }
    __syncthreads();

    const int res = lp.res[level];
    const int r2  = lp.r2mod[level];
    const v2f* __restrict__ e2 = (const v2f*)emb + (size_t)level * HSIZE;
    v2f* __restrict__ wl = ws + (size_t)level * npts;

    v2f v[K1_PPT];
    #pragma unroll
    for (int k = 0; k < K1_PPT; ++k) {
        const int pl = tid + k * 256;         // local point 0..K1_CHUNK-1
        if (base + pl < end) {
            const int h = hash_one(sx[pl * 3], sx[pl * 3 + 1], sx[pl * 3 + 2], res, r2);
            v[k] = e2[h];
        }
    }
    #pragma unroll
    for (int k = 0; k < K1_PPT; ++k) {
        const int p = base + tid + k * 256;
        if (p < end)
            __builtin_nontemporal_store(v[k], &wl[p]);   // nt: protect L2 tables
    }
}

// ---------------- K2: 7-level gather + LDS transpose ---------------------
// Gathers levels 0..6 directly (tables 0..6 ~ 10.4 MB: 0-4 L2-resident,
// 5-6 mostly L3 — K2 had ~40+ us of slack under K1, absorbing them here
// shrinks the serial K1). Heavy levels 7..15 stream from ws with nt loads
// issued FIRST so they fly under the hash math + gathers. All 16 levels
// land in LDS, then each wave writes point-major 1 KB-contiguous float4.
__global__ __launch_bounds__(256)
void hashgrid_finalize(const float* __restrict__ x,
                       const float* __restrict__ emb,
                       const v2f* __restrict__ ws,
                       v4f* __restrict__ out4,
                       LevelParams lp, int npts)
{
    __shared__ v2f sl[16][257];   // 32.9 KB; +1 pad spreads transpose banks

    const int tid = threadIdx.x;
    const int p0  = (int)blockIdx.x * 256;
    const int  p     = p0 + tid;
    const bool valid = (p < npts);

    // heavy levels 7..15 from workspace: contiguous 512 B per wave, nt
    v2f r[9];
    #pragma unroll
    for (int li = 0; li < 9; ++li) {
        r[li] = valid
              ? __builtin_nontemporal_load(&ws[(size_t)(7 + li) * npts + p])
              : (v2f)(0.0f);
    }

    const float x0 = valid ? x[p * 3 + 0] : 0.0f;
    const float x1 = valid ? x[p * 3 + 1] : 0.0f;
    const float x2 = valid ? x[p * 3 + 2] : 0.0f;

    // levels 0..6: own-point gathers (7 independent, in flight together)
    v2f g[7];
    #pragma unroll
    for (int l = 0; l < 7; ++l) {
        g[l] = valid
             ? ((const v2f*)emb)[(size_t)l * HSIZE + hash_one(x0, x1, x2, lp.res[l], lp.r2mod[l])]
             : (v2f)(0.0f);
    }

    #pragma unroll
    for (int l = 0; l < 7; ++l)    sl[l][tid]      = g[l];
    #pragma unroll
    for (int li = 0; li < 9; ++li) sl[7 + li][tid] = r[li];
    __syncthreads();

    const int j  = tid & 7;     // which float4 of the 32-float output row
    const int tq = tid >> 3;

    #pragma unroll
    for (int k = 0; k < 8; ++k) {
        const int pp = k * 32 + tq;           // point within tile, 0..255
        if (p0 + pp < npts) {
            const v2f va = sl[2 * j][pp];
            const v2f vb = sl[2 * j + 1][pp];
            v4f o; o.x = va.x; o.y = va.y; o.z = vb.x; o.w = vb.y;
            __builtin_nontemporal_store(o, &out4[(size_t)p0 * 8 + k * 256 + tid]);
        }
    }
}

// ---------------- fallback: proven round-1 single kernel -----------------
__global__ __launch_bounds__(256)
void hashgrid_fwd(const float* __restrict__ x,
                  const float* __restrict__ emb,
                  float* __restrict__ out,
                  LevelParams lp, int npts)
{
    __shared__ float sx[256 * 3];
    const int tid        = threadIdx.x;
    const int block_base = blockIdx.x * 256;
    const int nfl        = npts * 3;
    const int base3      = block_base * 3;
    #pragma unroll
    for (int k = 0; k < 3; ++k) {
        int idx = base3 + tid + k * 256;
        if (idx < nfl) sx[tid + k * 256] = x[idx];
    }
    __syncthreads();
    const int p = block_base + tid;
    if (p >= npts) return;
    const float x0 = sx[tid * 3 + 0], x1 = sx[tid * 3 + 1], x2 = sx[tid * 3 + 2];
    const float2* __restrict__ e2 = (const float2*)emb;
    float2 v[NLEVELS];
    #pragma unroll
    for (int l = 0; l < NLEVELS; ++l) {
        const int h = hash_one(x0, x1, x2, lp.res[l], lp.r2mod[l]);
        v[l] = e2[(size_t)l * HSIZE + h];
    }
    float4* __restrict__ o4 = (float4*)(out + (size_t)p * (NLEVELS * 2));
    #pragma unroll
    for (int i = 0; i < 8; ++i)
        o4[i] = make_float4(v[2 * i].x, v[2 * i].y, v[2 * i + 1].x, v[2 * i + 1].y);
}

extern "C" void kernel_launch(void* const* d_in, const int* in_sizes, int n_in,
                              void* d_out, int out_size, void* d_ws, size_t ws_size,
                              hipStream_t stream)
{
    const float* x   = (const float*)d_in[0];
    const float* emb = (const float*)d_in[1];
    float*       out = (float*)d_out;

    const int npts = in_sizes[0] / 3;

    // Host-double resolution computation, exact replica of the reference.
    LevelParams lp;
    const double s = std::exp((std::log(2048.0) - std::log(16.0)) / 15.0);
    for (int l = 0; l < NLEVELS; ++l) {
        const double r = 16.0 * std::pow(s, (double)l);
        const int res  = (int)r;
        lp.res[l]   = res;
        lp.r2mod[l] = (int)(((long long)res * res) % HSIZE);
    }

    const size_t ws_need = (size_t)NLEVELS * (size_t)npts * sizeof(v2f);
    if (ws_size >= ws_need) {
        const int cA      = (npts + K1_CHUNK - 1) / K1_CHUNK;
        const int blocksA = cA * 8;               // levels 7..14, all points
        // phase-B grid: level 15 sharded 8-way, chunk-aligned shards
        const int shardN  = (((npts + 7) / 8 + K1_CHUNK - 1) / K1_CHUNK) * K1_CHUNK;
        const int cB      = shardN / K1_CHUNK;
        const int grid1   = blocksA + cB * 8;
        hipLaunchKernelGGL(hashgrid_gather2, dim3(grid1), dim3(256), 0, stream,
                           x, emb, (v2f*)d_ws, lp, npts, blocksA);
        const int grid2 = (npts + 255) / 256;
        hipLaunchKernelGGL(hashgrid_finalize, dim3(grid2), dim3(256), 0, stream,
                           x, emb, (const v2f*)d_ws, (v4f*)out, lp, npts);
    } else {
        const int blocks = (npts + 255) / 256;
        hipLaunchKernelGGL(hashgrid_fwd, dim3(blocks), dim3(256), 0, stream,
                           x, emb, out, lp, npts);
    }
}